// Round 1
// baseline (193.689 us; speedup 1.0000x reference)
//
#include <hip/hip_runtime.h>

typedef unsigned short u16;
typedef unsigned int u32;
typedef __attribute__((ext_vector_type(4))) float f32x4;
typedef __attribute__((ext_vector_type(4))) u16 u16x4;
typedef __attribute__((ext_vector_type(8))) u16 u16x8;
typedef __attribute__((ext_vector_type(8))) __bf16 bf16x8;

#define DEV static __device__ __forceinline__

DEV u16 f2b(float f) {
  u32 u = __builtin_bit_cast(u32, f);
  u32 r = (u + 0x7fffu + ((u >> 16) & 1u)) >> 16;
  return (u16)r;
}

DEV bf16x8 mk8(u16x4 lo, u16x4 hi) {
  u16x8 v = __builtin_shufflevector(lo, hi, 0, 1, 2, 3, 4, 5, 6, 7);
  return __builtin_bit_cast(bf16x8, v);
}

// ---------------------------------------------------------------------------
// Stage 1: QKV projection.  X[128,512]f32 @ W[512,65536]f32 + b -> bf16 out.
// grid (512, 3), block 256.  Tile: BM=128 (all of M), BN=128, BK=64.
// LDS layout: [kq][row][4] (kq = k/4) -> contiguous, conflict-free b64 frag reads.
// As uses row-rotation (m + 2*kq) to avoid 16-way write conflicts.
// ---------------------------------------------------------------------------
__global__ __launch_bounds__(256) void qkv_proj(
    const float* __restrict__ key, const float* __restrict__ value, const float* __restrict__ query,
    const float* __restrict__ Wk, const float* __restrict__ bk,
    const float* __restrict__ Wv, const float* __restrict__ bv,
    const float* __restrict__ Wq, const float* __restrict__ bq,
    u16* __restrict__ Kp, u16* __restrict__ Vp, u16* __restrict__ Qp)
{
  const int mat = blockIdx.y;
  const float* X    = mat == 0 ? key : (mat == 1 ? value : query);
  const float* W    = mat == 0 ? Wk  : (mat == 1 ? Wv    : Wq);
  const float* bias = mat == 0 ? bk  : (mat == 1 ? bv    : bq);
  u16* out          = mat == 0 ? Kp  : (mat == 1 ? Vp    : Qp);
  const int n0 = blockIdx.x * 128;

  __shared__ u16 As[16 * 512];  // [kq][128 m (rotated)][4]
  __shared__ u16 Bs[16 * 512];  // [kq][128 n][4]

  const int t = threadIdx.x;
  const int lane = t & 63, wid = t >> 6;
  const int wm = wid >> 1, wn = wid & 1;
  const int l15 = lane & 15, lg = lane >> 4;

  f32x4 acc[4][4];
#pragma unroll
  for (int i = 0; i < 4; ++i)
#pragma unroll
    for (int j = 0; j < 4; ++j) acc[i][j] = (f32x4){0.f, 0.f, 0.f, 0.f};

  for (int it = 0; it < 8; ++it) {
    const int k0 = it * 64;
    // stage A (X tile 128x64 f32 -> bf16)
#pragma unroll
    for (int p = 0; p < 8; ++p) {
      int idx = p * 256 + t;
      int m = idx >> 4, kq = idx & 15;
      f32x4 xv = *(const f32x4*)(X + m * 512 + k0 + kq * 4);
      u16x4 uv;
      uv[0] = f2b(xv[0]); uv[1] = f2b(xv[1]); uv[2] = f2b(xv[2]); uv[3] = f2b(xv[3]);
      *(u16x4*)(As + kq * 512 + (((m + 2 * kq) & 127) << 2)) = uv;
    }
    // stage B (W tile 64x128 f32 -> bf16, k-blocked layout)
#pragma unroll
    for (int p = 0; p < 8; ++p) {
      int idx = p * 256 + t;
      int n = idx & 127, kq = idx >> 7;
      const float* wp = W + (size_t)(k0 + kq * 4) * 65536 + n0 + n;
      u16x4 uv;
      uv[0] = f2b(wp[0]);
      uv[1] = f2b(wp[65536]);
      uv[2] = f2b(wp[2 * 65536]);
      uv[3] = f2b(wp[3 * 65536]);
      *(u16x4*)(Bs + kq * 512 + n * 4) = uv;
    }
    __syncthreads();
#pragma unroll
    for (int kstep = 0; kstep < 2; ++kstep) {
      const int kqA = kstep * 8 + lg * 2;
      bf16x8 af[4], bfr[4];
#pragma unroll
      for (int mf = 0; mf < 4; ++mf) {
        int m = wm * 64 + mf * 16 + l15;
        u16x4 lo = *(const u16x4*)(As + kqA * 512 + (((m + 2 * kqA) & 127) << 2));
        u16x4 hi = *(const u16x4*)(As + (kqA + 1) * 512 + (((m + 2 * (kqA + 1)) & 127) << 2));
        af[mf] = mk8(lo, hi);
      }
#pragma unroll
      for (int nf = 0; nf < 4; ++nf) {
        int n = wn * 64 + nf * 16 + l15;
        u16x4 lo = *(const u16x4*)(Bs + kqA * 512 + n * 4);
        u16x4 hi = *(const u16x4*)(Bs + (kqA + 1) * 512 + n * 4);
        bfr[nf] = mk8(lo, hi);
      }
#pragma unroll
      for (int mf = 0; mf < 4; ++mf)
#pragma unroll
        for (int nf = 0; nf < 4; ++nf)
          acc[mf][nf] = __builtin_amdgcn_mfma_f32_16x16x32_bf16(af[mf], bfr[nf], acc[mf][nf], 0, 0, 0);
    }
    __syncthreads();
  }

  // epilogue: + bias, -> bf16
#pragma unroll
  for (int nf = 0; nf < 4; ++nf) {
    int col = wn * 64 + nf * 16 + l15;
    float bv_ = bias[n0 + col];
#pragma unroll
    for (int mf = 0; mf < 4; ++mf) {
      int row0 = wm * 64 + mf * 16 + lg * 4;
#pragma unroll
      for (int r = 0; r < 4; ++r) {
        out[(size_t)(row0 + r) * 65536 + n0 + col] = f2b(acc[mf][nf][r] + bv_);
      }
    }
  }
}

// ---------------------------------------------------------------------------
// Stage 2: attention per (b,h).  q,k,v [128,32] bf16.  grid 2048, block 256.
// S = q k^T * scale (MFMA), row softmax, attn->f32 out, P->LDS bf16, PV (MFMA),
// ctx -> ws bf16 in the reference's reshape layout.
// ---------------------------------------------------------------------------
__global__ __launch_bounds__(256) void attn_kernel(
    const u16* __restrict__ Qp, const u16* __restrict__ Kp, const u16* __restrict__ Vp,
    float* __restrict__ attnOut, u16* __restrict__ ctx)
{
  const int bh = blockIdx.x;
  const int b = bh >> 4, h = bh & 15;
  const size_t base = (size_t)b * 65536 + h * 4096;

  __shared__ u16 qS[8 * 512];   // [kq_d][128 s][4]
  __shared__ u16 kS[8 * 512];   // [kq_d][128 j][4]
  __shared__ u16 vS[32 * 128];  // [kq_j][32 d][4]
  __shared__ u16 pS[32 * 512];  // [kq_j][128 i][4]

  const int t = threadIdx.x;
  const int lane = t & 63, w = t >> 6;
  const int l15 = lane & 15, lg = lane >> 4;

  // stage q, k, v
#pragma unroll
  for (int p = 0; p < 2; ++p) {
    int idx = p * 256 + t;          // 0..511
    int s = idx >> 2, dc = idx & 3; // 8 d per chunk
    u16x8 qv = *(const u16x8*)(Qp + base + s * 32 + dc * 8);
    u16x8 kv = *(const u16x8*)(Kp + base + s * 32 + dc * 8);
    u16x8 vv = *(const u16x8*)(Vp + base + s * 32 + dc * 8);
    *(u16x4*)(qS + (dc * 2) * 512 + s * 4)     = __builtin_shufflevector(qv, qv, 0, 1, 2, 3);
    *(u16x4*)(qS + (dc * 2 + 1) * 512 + s * 4) = __builtin_shufflevector(qv, qv, 4, 5, 6, 7);
    *(u16x4*)(kS + (dc * 2) * 512 + s * 4)     = __builtin_shufflevector(kv, kv, 0, 1, 2, 3);
    *(u16x4*)(kS + (dc * 2 + 1) * 512 + s * 4) = __builtin_shufflevector(kv, kv, 4, 5, 6, 7);
#pragma unroll
    for (int i = 0; i < 8; ++i)
      vS[(s >> 2) * 128 + (dc * 8 + i) * 4 + (s & 3)] = vv[i];
  }
  __syncthreads();

  // QK^T: wave w owns rows w*32..w*32+31, all 128 cols
  f32x4 sc[2][8];
#pragma unroll
  for (int i = 0; i < 2; ++i)
#pragma unroll
    for (int j = 0; j < 8; ++j) sc[i][j] = (f32x4){0.f, 0.f, 0.f, 0.f};

  {
    const int kqA = lg * 2;  // K-dim = 32: single MFMA k-step
    bf16x8 aq[2];
#pragma unroll
    for (int mf = 0; mf < 2; ++mf) {
      int m = w * 32 + mf * 16 + l15;
      u16x4 lo = *(const u16x4*)(qS + kqA * 512 + m * 4);
      u16x4 hi = *(const u16x4*)(qS + (kqA + 1) * 512 + m * 4);
      aq[mf] = mk8(lo, hi);
    }
#pragma unroll
    for (int nf = 0; nf < 8; ++nf) {
      int j = nf * 16 + l15;
      u16x4 lo = *(const u16x4*)(kS + kqA * 512 + j * 4);
      u16x4 hi = *(const u16x4*)(kS + (kqA + 1) * 512 + j * 4);
      bf16x8 bk8 = mk8(lo, hi);
#pragma unroll
      for (int mf = 0; mf < 2; ++mf)
        sc[mf][nf] = __builtin_amdgcn_mfma_f32_16x16x32_bf16(aq[mf], bk8, sc[mf][nf], 0, 0, 0);
    }
  }

  // softmax over j (scale applied inside exp), write attn f32 + P bf16 to LDS
  const float SCL = 0.70710678118654752f;
#pragma unroll
  for (int mf = 0; mf < 2; ++mf) {
#pragma unroll
    for (int r = 0; r < 4; ++r) {
      float m8 = -1e30f;
#pragma unroll
      for (int nf = 0; nf < 8; ++nf) m8 = fmaxf(m8, sc[mf][nf][r]);
      m8 = fmaxf(m8, __shfl_xor(m8, 1));
      m8 = fmaxf(m8, __shfl_xor(m8, 2));
      m8 = fmaxf(m8, __shfl_xor(m8, 4));
      m8 = fmaxf(m8, __shfl_xor(m8, 8));
      float s8 = 0.f;
#pragma unroll
      for (int nf = 0; nf < 8; ++nf) {
        float pv = __expf((sc[mf][nf][r] - m8) * SCL);
        sc[mf][nf][r] = pv;
        s8 += pv;
      }
      s8 += __shfl_xor(s8, 1);
      s8 += __shfl_xor(s8, 2);
      s8 += __shfl_xor(s8, 4);
      s8 += __shfl_xor(s8, 8);
      float inv = 1.0f / s8;
      int i = w * 32 + mf * 16 + lg * 4 + r;
      float* ao = attnOut + (size_t)bh * 16384 + (size_t)i * 128;
#pragma unroll
      for (int nf = 0; nf < 8; ++nf) {
        int j = nf * 16 + l15;
        float pv = sc[mf][nf][r] * inv;
        ao[j] = pv;
        pS[(j >> 2) * 512 + i * 4 + (j & 3)] = f2b(pv);
      }
    }
  }
  __syncthreads();

  // PV: context rows w*32..+31, d = 0..31
  f32x4 cacc[2][2];
#pragma unroll
  for (int i = 0; i < 2; ++i)
#pragma unroll
    for (int j = 0; j < 2; ++j) cacc[i][j] = (f32x4){0.f, 0.f, 0.f, 0.f};

#pragma unroll
  for (int ks2 = 0; ks2 < 4; ++ks2) {
    const int kqP = ks2 * 8 + lg * 2;
    bf16x8 ap[2];
#pragma unroll
    for (int mf = 0; mf < 2; ++mf) {
      int i = w * 32 + mf * 16 + l15;
      u16x4 lo = *(const u16x4*)(pS + kqP * 512 + i * 4);
      u16x4 hi = *(const u16x4*)(pS + (kqP + 1) * 512 + i * 4);
      ap[mf] = mk8(lo, hi);
    }
#pragma unroll
    for (int nf = 0; nf < 2; ++nf) {
      int d = nf * 16 + l15;
      u16x4 lo = *(const u16x4*)(vS + kqP * 128 + d * 4);
      u16x4 hi = *(const u16x4*)(vS + (kqP + 1) * 128 + d * 4);
      bf16x8 bv8 = mk8(lo, hi);
#pragma unroll
      for (int mf = 0; mf < 2; ++mf)
        cacc[mf][nf] = __builtin_amdgcn_mfma_f32_16x16x32_bf16(ap[mf], bv8, cacc[mf][nf], 0, 0, 0);
    }
  }

  // ctx write in reshape layout: p = h*8 + (s>>4), c = (s&15)*32 + d
#pragma unroll
  for (int mf = 0; mf < 2; ++mf) {
#pragma unroll
    for (int r = 0; r < 4; ++r) {
      int s = w * 32 + mf * 16 + lg * 4 + r;
      size_t rowbase = ((size_t)b * 128 + h * 8 + (s >> 4)) * 512 + (s & 15) * 32;
#pragma unroll
      for (int nf = 0; nf < 2; ++nf) {
        int d = nf * 16 + l15;
        ctx[rowbase + d] = f2b(cacc[mf][nf][r]);
      }
    }
  }
}

// ---------------------------------------------------------------------------
// Stage 3a: out = ctx[16384,512]bf16 @ Wo[512,512]f32 + bo + residual -> f32 pre
// grid (128, 4), block 256.
// ---------------------------------------------------------------------------
__global__ __launch_bounds__(256) void out_proj(
    const u16* __restrict__ ctx, const float* __restrict__ Wo, const float* __restrict__ bo,
    const float* __restrict__ query, float* __restrict__ pre)
{
  const int m0 = blockIdx.x * 128;
  const int n0 = blockIdx.y * 128;

  __shared__ u16 As[16 * 512];
  __shared__ u16 Bs[16 * 512];

  const int t = threadIdx.x;
  const int lane = t & 63, wid = t >> 6;
  const int wm = wid >> 1, wn = wid & 1;
  const int l15 = lane & 15, lg = lane >> 4;

  f32x4 acc[4][4];
#pragma unroll
  for (int i = 0; i < 4; ++i)
#pragma unroll
    for (int j = 0; j < 4; ++j) acc[i][j] = (f32x4){0.f, 0.f, 0.f, 0.f};

  for (int it = 0; it < 8; ++it) {
    const int k0 = it * 64;
#pragma unroll
    for (int p = 0; p < 4; ++p) {
      int idx = p * 256 + t;          // 0..1023
      int m = idx >> 3, dc = idx & 7; // 8 chunks of 8 per row
      u16x8 av = *(const u16x8*)(ctx + (size_t)(m0 + m) * 512 + k0 + dc * 8);
      int kq = dc * 2;
      *(u16x4*)(As + kq * 512 + (((m + 2 * kq) & 127) << 2)) =
          __builtin_shufflevector(av, av, 0, 1, 2, 3);
      *(u16x4*)(As + (kq + 1) * 512 + (((m + 2 * (kq + 1)) & 127) << 2)) =
          __builtin_shufflevector(av, av, 4, 5, 6, 7);
    }
#pragma unroll
    for (int p = 0; p < 8; ++p) {
      int idx = p * 256 + t;
      int n = idx & 127, kq = idx >> 7;
      const float* wp = Wo + (size_t)(k0 + kq * 4) * 512 + n0 + n;
      u16x4 uv;
      uv[0] = f2b(wp[0]);
      uv[1] = f2b(wp[512]);
      uv[2] = f2b(wp[1024]);
      uv[3] = f2b(wp[1536]);
      *(u16x4*)(Bs + kq * 512 + n * 4) = uv;
    }
    __syncthreads();
#pragma unroll
    for (int kstep = 0; kstep < 2; ++kstep) {
      const int kqA = kstep * 8 + lg * 2;
      bf16x8 af[4], bfr[4];
#pragma unroll
      for (int mf = 0; mf < 4; ++mf) {
        int m = wm * 64 + mf * 16 + l15;
        u16x4 lo = *(const u16x4*)(As + kqA * 512 + (((m + 2 * kqA) & 127) << 2));
        u16x4 hi = *(const u16x4*)(As + (kqA + 1) * 512 + (((m + 2 * (kqA + 1)) & 127) << 2));
        af[mf] = mk8(lo, hi);
      }
#pragma unroll
      for (int nf = 0; nf < 4; ++nf) {
        int n = wn * 64 + nf * 16 + l15;
        u16x4 lo = *(const u16x4*)(Bs + kqA * 512 + n * 4);
        u16x4 hi = *(const u16x4*)(Bs + (kqA + 1) * 512 + n * 4);
        bfr[nf] = mk8(lo, hi);
      }
#pragma unroll
      for (int mf = 0; mf < 4; ++mf)
#pragma unroll
        for (int nf = 0; nf < 4; ++nf)
          acc[mf][nf] = __builtin_amdgcn_mfma_f32_16x16x32_bf16(af[mf], bfr[nf], acc[mf][nf], 0, 0, 0);
    }
    __syncthreads();
  }

#pragma unroll
  for (int nf = 0; nf < 4; ++nf) {
    int col = wn * 64 + nf * 16 + l15;
    float bv_ = bo[n0 + col];
#pragma unroll
    for (int mf = 0; mf < 4; ++mf) {
      int row0 = wm * 64 + mf * 16 + lg * 4;
#pragma unroll
      for (int r = 0; r < 4; ++r) {
        int m = m0 + row0 + r;
        float res = query[(m >> 7) * 512 + n0 + col];
        pre[(size_t)m * 512 + n0 + col] = acc[mf][nf][r] + bv_ + res;
      }
    }
  }
}

// ---------------------------------------------------------------------------
// Stage 3b: LayerNorm over last dim (512).  One wave per row. grid 4096, blk 256.
// ---------------------------------------------------------------------------
__global__ __launch_bounds__(256) void ln_kernel(
    const float* __restrict__ pre, const float* __restrict__ gamma,
    const float* __restrict__ beta, float* __restrict__ out0)
{
  const int w = threadIdx.x >> 6, lane = threadIdx.x & 63;
  const int row = blockIdx.x * 4 + w;
  const float* x = pre + (size_t)row * 512;
  f32x4 v0 = *(const f32x4*)(x + lane * 8);
  f32x4 v1 = *(const f32x4*)(x + lane * 8 + 4);
  float s = v0[0] + v0[1] + v0[2] + v0[3] + v1[0] + v1[1] + v1[2] + v1[3];
  float q = v0[0] * v0[0] + v0[1] * v0[1] + v0[2] * v0[2] + v0[3] * v0[3] +
            v1[0] * v1[0] + v1[1] * v1[1] + v1[2] * v1[2] + v1[3] * v1[3];
#pragma unroll
  for (int m = 1; m < 64; m <<= 1) {
    s += __shfl_xor(s, m);
    q += __shfl_xor(q, m);
  }
  float mean = s * (1.f / 512.f);
  float var = q * (1.f / 512.f) - mean * mean;
  float rs = rsqrtf(var + 1e-5f);
  f32x4 g0 = *(const f32x4*)(gamma + lane * 8);
  f32x4 g1 = *(const f32x4*)(gamma + lane * 8 + 4);
  f32x4 b0 = *(const f32x4*)(beta + lane * 8);
  f32x4 b1 = *(const f32x4*)(beta + lane * 8 + 4);
  f32x4 o0, o1;
#pragma unroll
  for (int i = 0; i < 4; ++i) {
    o0[i] = (v0[i] - mean) * rs * g0[i] + b0[i];
    o1[i] = (v1[i] - mean) * rs * g1[i] + b1[i];
  }
  *(f32x4*)(out0 + (size_t)row * 512 + lane * 8) = o0;
  *(f32x4*)(out0 + (size_t)row * 512 + lane * 8 + 4) = o1;
}

// ---------------------------------------------------------------------------
extern "C" void kernel_launch(void* const* d_in, const int* in_sizes, int n_in,
                              void* d_out, int out_size, void* d_ws, size_t ws_size,
                              hipStream_t stream) {
  (void)in_sizes; (void)n_in; (void)out_size; (void)ws_size;
  const float* key   = (const float*)d_in[0];
  const float* value = (const float*)d_in[1];
  const float* query = (const float*)d_in[2];
  const float* Wk    = (const float*)d_in[3];
  const float* bk    = (const float*)d_in[4];
  const float* Wv    = (const float*)d_in[5];
  const float* bv    = (const float*)d_in[6];
  const float* Wq    = (const float*)d_in[7];
  const float* bq    = (const float*)d_in[8];
  const float* Wo    = (const float*)d_in[9];
  const float* bo    = (const float*)d_in[10];
  const float* gamma = (const float*)d_in[11];
  const float* beta  = (const float*)d_in[12];

  char* ws = (char*)d_ws;
  u16* Kp  = (u16*)(ws + 0);               // 16 MB  (128 x 65536 bf16)
  u16* Vp  = (u16*)(ws + 16777216);        // 16 MB
  u16* Qp  = (u16*)(ws + 33554432);        // 16 MB
  u16* ctx = (u16*)(ws + 50331648);        // 16 MB  (16384 x 512 bf16)
  float* pre = (float*)(ws + 0);           // 32 MB, overlays dead K/V after attn

  float* out0    = (float*)d_out;          // [128,128,512] LN result
  float* attnOut = out0 + 8388608;         // [2048,128,128] attn

  qkv_proj<<<dim3(512, 3), 256, 0, stream>>>(key, value, query, Wk, bk, Wv, bv, Wq, bq, Kp, Vp, Qp);
  attn_kernel<<<dim3(2048), 256, 0, stream>>>(Qp, Kp, Vp, attnOut, ctx);
  out_proj<<<dim3(128, 4), 256, 0, stream>>>(ctx, Wo, bo, query, pre);
  ln_kernel<<<dim3(4096), 256, 0, stream>>>(pre, gamma, beta, out0);
}